// Round 10
// baseline (121.272 us; speedup 1.0000x reference)
//
#include <hip/hip_runtime.h>
#include <hip/hip_bf16.h>

#define NF 16
#define NH 32
#define LOG2E  1.44269504088896340736f
#define TILE 32

// per-wave LDS input staging (float words): x 512 + h 1024 = 6KB
#define IN_WORDS 1536
#define XW 0
#define HW 512
// out-transpose overlay (inside the consumed input buffer): 32 rows x 33
#define OSTG 33
#define OSTG_WORDS (32 * OSTG)   // 1056 <= 1536

typedef short bf16x8 __attribute__((ext_vector_type(8)));
typedef float f32x16 __attribute__((ext_vector_type(16)));
typedef float f32x4  __attribute__((ext_vector_type(4)));

#if __has_builtin(__builtin_amdgcn_exp2f)
#define EXP2(x) __builtin_amdgcn_exp2f(x)
#else
#define EXP2(x) exp2f(x)
#endif

__device__ __forceinline__ short f2bf(float f) {
    __hip_bfloat16 b = __float2bfloat16(f);  // RNE
    return *reinterpret_cast<short*>(&b);
}

__device__ __forceinline__ bf16x8 cvt8(float4 a, float4 b) {
    bf16x8 r;
    r[0] = f2bf(a.x); r[1] = f2bf(a.y); r[2] = f2bf(a.z); r[3] = f2bf(a.w);
    r[4] = f2bf(b.x); r[5] = f2bf(b.y); r[6] = f2bf(b.z); r[7] = f2bf(b.w);
    return r;
}

__device__ __forceinline__ float sig2(float v) {   // arg pre-scaled by log2e
    return __builtin_amdgcn_rcpf(1.0f + EXP2(-v));
}
__device__ __forceinline__ float tanh2(float v) {  // arg pre-scaled by 2*log2e
    return 1.0f - 2.0f * __builtin_amdgcn_rcpf(1.0f + EXP2(v));
}

// async global->LDS, 16B per lane, LDS dest = uniform base + lane*16
__device__ __forceinline__ void gload_lds16(const float* g, float* l) {
    __builtin_amdgcn_global_load_lds(
        (const __attribute__((address_space(1))) void*)g,
        (__attribute__((address_space(3))) void*)l, 16, 0, 0);
}

// non-temporal 16B store (clang ext_vector type required by the builtin)
__device__ __forceinline__ void nt_store4(float* p, float4 v) {
    f32x4 w = { v.x, v.y, v.z, v.w };
    __builtin_nontemporal_store(w, (f32x4*)p);
}

struct Frags { bf16x8 w[4][4]; bf16x8 a3; };

// ---------------------------------------------------------------------------
// Prep: pack W' = [Wx; Wh; bias; pad] (64x32 per gate, pre-scaled by log2e,
// gate 2 by 2*log2e) into MFMA A-operand fragments. wcs = scaled peephole.
// ---------------------------------------------------------------------------
__global__ void prep_kernel(const float* __restrict__ Wx, const float* __restrict__ Wh,
                            const float* __restrict__ bx, const float* __restrict__ bh,
                            const float* __restrict__ bg, const float* __restrict__ wc,
                            short* __restrict__ Wpack, float* __restrict__ wcs)
{
    int t = blockIdx.x * blockDim.x + threadIdx.x;
    if (t < 4 * 4 * 64) {
        int g  = t >> 8;
        int ks = (t >> 6) & 3;
        int l  = t & 63;
        int col  = l & 31;
        int half = l >> 5;
        float scale = (g == 2) ? 2.0f * LOG2E : LOG2E;
        #pragma unroll
        for (int e = 0; e < 8; ++e) {
            int gk = ks * 16 + half * 8 + e;
            float w;
            if (gk < NF)            w = Wx[(g * NF + gk) * NH + col];
            else if (gk < NF + NH)  w = Wh[(g * NH + (gk - NF)) * NH + col];
            else if (gk == 48)      w = bx[g * NH + col] + bh[g * NH + col] + bg[g * NH + col];
            else                    w = 0.0f;
            Wpack[t * 8 + e] = f2bf(w * scale);
        }
    }
    if (t < 3 * NH) wcs[t] = wc[t] * LOG2E;
}

// ---------------------------------------------------------------------------
// DMA-prefetch x,h of one 32-node tile (6 global_load_lds; sources
// XOR-pre-swizzled so fragment reads are balanced across banks).
// ---------------------------------------------------------------------------
__device__ __forceinline__ void prefetch_xh(const float* __restrict__ x,
                                            const float* __restrict__ hin,
                                            long nb, float* ws,
                                            const int* xoff, const int* hoff)
{
    asm volatile("" ::: "memory");
    const float* xb = x   + nb * NF;
    const float* hb = hin + nb * NH;
    #pragma unroll
    for (int i = 0; i < 2; ++i) gload_lds16(xb + xoff[i], ws + XW + i * 256);
    #pragma unroll
    for (int i = 0; i < 4; ++i) gload_lds16(hb + hoff[i], ws + HW + i * 256);
    asm volatile("" ::: "memory");
}

// c prefetch straight to registers (lane owns node nb+col; 4x float4;
// j = (r&3)+8*(r>>2)+4*half matches acc layout)
#define LOAD_C(cr, t_) {                                                     \
    const float* pc = cin + ((long)(t_) * TILE + col) * NH + 4 * half;       \
    cr[0] = *(const float4*)(pc);      cr[1] = *(const float4*)(pc + 8);     \
    cr[2] = *(const float4*)(pc + 16); cr[3] = *(const float4*)(pc + 24);    \
    asm volatile("" ::: "memory"); }

// ---------------------------------------------------------------------------
// Consume one staged tile. Swapped-operand MFMA: D[row=j][col=node]; lane
// owns node nb+(lane&31). Output transpose overlays the consumed input
// buffer: h-stage then c-stage sequentially through one stride-33 region.
// ---------------------------------------------------------------------------
__device__ __forceinline__ void do_tile(float* ws, long nb,
                                        const float4* cr, const Frags& F,
                                        const float* __restrict__ wcs,
                                        const float* __restrict__ Wlin, float bl,
                                        float* __restrict__ out,
                                        float* __restrict__ h0o,
                                        float* __restrict__ co, int lane)
{
    const int col  = lane & 31;
    const int half = lane >> 5;
    const int c3 = col & 3, c7 = col & 7;

    // ---- fragment reads from LDS (match prefetch swizzle) ----
    float4 x0 = *(const float4*)&ws[XW + (col * 4 + ((2 * half)     ^ c3)) * 4];
    float4 x1 = *(const float4*)&ws[XW + (col * 4 + ((2 * half + 1) ^ c3)) * 4];
    float4 h0 = *(const float4*)&ws[HW + (col * 8 + ((2 * half)     ^ c7)) * 4];
    float4 h1 = *(const float4*)&ws[HW + (col * 8 + ((2 * half + 1) ^ c7)) * 4];
    float4 h2 = *(const float4*)&ws[HW + (col * 8 + ((4 + 2 * half) ^ c7)) * 4];
    float4 h3 = *(const float4*)&ws[HW + (col * 8 + ((5 + 2 * half) ^ c7)) * 4];
    bf16x8 a0 = cvt8(x0, x1), a1 = cvt8(h0, h1), a2 = cvt8(h2, h3);

    // ---- 16 MFMAs: 4 gates x K=64 (bias folded into ks=3) ----
    f32x16 acc[4];
    #pragma unroll
    for (int g = 0; g < 4; ++g) {
        #pragma unroll
        for (int r = 0; r < 16; ++r) acc[g][r] = 0.0f;
        acc[g] = __builtin_amdgcn_mfma_f32_32x32x16_bf16(F.w[g][0], a0,   acc[g], 0, 0, 0);
        acc[g] = __builtin_amdgcn_mfma_f32_32x32x16_bf16(F.w[g][1], a1,   acc[g], 0, 0, 0);
        acc[g] = __builtin_amdgcn_mfma_f32_32x32x16_bf16(F.w[g][2], a2,   acc[g], 0, 0, 0);
        acc[g] = __builtin_amdgcn_mfma_f32_32x32x16_bf16(F.w[g][3], F.a3, acc[g], 0, 0, 0);
    }

    // ---- epilogue: gates; h via LDS overlay (input consumed), c in regs ----
    float outacc = 0.0f;
    const float c2l = 2.0f * LOG2E;
    float c4s0[4], c4s1[4], c4s2[4], c4s3[4];   // static-indexed c_new carry
    #pragma unroll
    for (int jg = 0; jg < 4; ++jg) {
        const int jbase = jg * 8 + 4 * half;
        const float4 w0 = *(const float4*)(wcs + 0 * NH + jbase);
        const float4 w1 = *(const float4*)(wcs + 1 * NH + jbase);
        const float4 w2 = *(const float4*)(wcs + 2 * NH + jbase);
        const float4 wl = *(const float4*)(Wlin + jbase);
        float h4[4];
        #pragma unroll
        for (int q = 0; q < 4; ++q) {
            const int r = jg * 4 + q;
            const float ci = ((const float*)&cr[jg])[q];
            const float ig = sig2(fmaf(((const float*)&w0)[q], ci, acc[0][r]));
            const float fg = sig2(fmaf(((const float*)&w1)[q], ci, acc[1][r]));
            const float tg = tanh2(acc[2][r]);
            const float cn = fg * ci + ig * tg;
            const float og = sig2(fmaf(((const float*)&w2)[q], cn, acc[3][r]));
            const float hh = og * tanh2(cn * c2l);
            if (jg == 0) c4s0[q] = cn; else if (jg == 1) c4s1[q] = cn;
            else if (jg == 2) c4s2[q] = cn; else c4s3[q] = cn;
            h4[q] = hh;
            outacc = fmaf(fmaxf(hh, 0.0f), ((const float*)&wl)[q], outacc);
        }
        *(float4*)&ws[col * OSTG + jbase] = make_float4(h4[0], h4[1], h4[2], h4[3]);
    }

    // ---- h write-back: transpose read + coalesced NT rows ----
    float* hrow = h0o + nb * NH;
    float* crow = co  + nb * NH;
    #pragma unroll
    for (int rep = 0; rep < 4; ++rep) {
        const int tt = lane + rep * 64;
        float4 vh = *(const float4*)&ws[(tt >> 3) * OSTG + (tt & 7) * 4];
        nt_store4(hrow + tt * 4, vh);
    }

    // ---- c write-back: same overlay region, sequentially (DS in-order) ----
    {
        const int jb0 = 4 * half;
        *(float4*)&ws[col * OSTG + jb0]      = make_float4(c4s0[0], c4s0[1], c4s0[2], c4s0[3]);
        *(float4*)&ws[col * OSTG + jb0 + 8]  = make_float4(c4s1[0], c4s1[1], c4s1[2], c4s1[3]);
        *(float4*)&ws[col * OSTG + jb0 + 16] = make_float4(c4s2[0], c4s2[1], c4s2[2], c4s2[3]);
        *(float4*)&ws[col * OSTG + jb0 + 24] = make_float4(c4s3[0], c4s3[1], c4s3[2], c4s3[3]);
    }
    #pragma unroll
    for (int rep = 0; rep < 4; ++rep) {
        const int tt = lane + rep * 64;
        float4 vc = *(const float4*)&ws[(tt >> 3) * OSTG + (tt & 7) * 4];
        nt_store4(crow + tt * 4, vc);
    }

    outacc += __shfl_xor(outacc, 32, 64);
    if (half == 0) __builtin_nontemporal_store(outacc + bl, &out[nb + col]);
}

// ---------------------------------------------------------------------------
// Persistent pipeline (R7 ordering), 3 blocks/CU. FIFO per steady iter:
//   [DMA(t)6, c(t)4, stores(t-1)9, DMA(t+1)6, c(t+1)4] -> vmcnt(23) drains
//   exactly DMA(t); c-load waits are compiler-automatic; stores get a
//   full-iteration retirement leash.
// ---------------------------------------------------------------------------
__global__ __launch_bounds__(256, 3) void lstm_pipe_kernel(
    const float* __restrict__ x, const float* __restrict__ hin,
    const float* __restrict__ cin,
    const float* __restrict__ Wlin, const float* __restrict__ blin,
    const short* __restrict__ Wpack, const float* __restrict__ wcs,
    float* __restrict__ out, float* __restrict__ h0o, float* __restrict__ co,
    int ntiles, int wstride)
{
    __shared__ float bufA[4][IN_WORDS];   // 24 KB
    __shared__ float bufB[4][IN_WORDS];   // 24 KB -> 48 KB total, 3 blocks/CU

    const int lane = threadIdx.x & 63;
    const int wave = threadIdx.x >> 6;
    const int col  = lane & 31;
    const int half = lane >> 5;
    float* cur = bufA[wave];
    float* oth = bufB[wave];

    Frags F;
    #pragma unroll
    for (int g = 0; g < 4; ++g)
        #pragma unroll
        for (int ks = 0; ks < 4; ++ks)
            F.w[g][ks] = *(const bf16x8*)(Wpack + (((g * 4) + ks) * 64 + lane) * 8);
    #pragma unroll
    for (int e = 0; e < 8; ++e) F.a3[e] = 0;
    if (half == 0) F.a3[0] = (short)0x3F80;  // bf16 1.0 at k=48
    const float bl = blin[0];

    int xoff[2], hoff[4];
    #pragma unroll
    for (int i = 0; i < 2; ++i) {
        int u = i * 64 + lane;
        xoff[i] = ((u & ~3) | ((u & 3) ^ ((u >> 2) & 3))) * 4;
    }
    #pragma unroll
    for (int i = 0; i < 4; ++i) {
        int u = i * 64 + lane;
        hoff[i] = ((u & ~7) | ((u & 7) ^ ((u >> 3) & 7))) * 4;
    }

    const int S = wstride;
    const int last = ntiles - 1;
    int t = blockIdx.x * 4 + wave;       // 3072 waves <= 15625 tiles

    float4 crA[4], crB[4];

    // prologue: L(t)->A, L(t+S)->B   [outstanding: 6+4+6+4 = 20]
    prefetch_xh(x, hin, (long)t * TILE, cur, xoff, hoff);
    LOAD_C(crA, t);
    {
        int t1 = t + S; if (t1 > last) t1 = last;
        prefetch_xh(x, hin, (long)t1 * TILE, oth, xoff, hoff);
        LOAD_C(crB, t1);
    }

    bool first = true;
    for (;;) {
        if (first) { asm volatile("s_waitcnt vmcnt(14)" ::: "memory"); first = false; }
        else       { asm volatile("s_waitcnt vmcnt(23)" ::: "memory"); }

        do_tile(cur, (long)t * TILE,
                ((t / S) & 1) ? crB : crA,   // parity-free: see swap below
                F, wcs, Wlin, bl, out, h0o, co, lane);

        int tn = t + 2 * S; if (tn > last) tn = last;  // clamped dup keeps counts uniform
        prefetch_xh(x, hin, (long)tn * TILE, cur, xoff, hoff);
        if (((t / S) & 1) == 0) { LOAD_C(crA, tn); } else { LOAD_C(crB, tn); }

        t += S;
        if (t >= ntiles) break;
        float* tmp = cur; cur = oth; oth = tmp;
    }
}

extern "C" void kernel_launch(void* const* d_in, const int* in_sizes, int n_in,
                              void* d_out, int out_size, void* d_ws, size_t ws_size,
                              hipStream_t stream) {
    const float* x    = (const float*)d_in[0];
    // d_in[1] = edge_index (unused, K=1 ChebConv), d_in[2] = edge_weight (unused)
    const float* h    = (const float*)d_in[3];
    const float* c    = (const float*)d_in[4];
    const float* Wx   = (const float*)d_in[5];
    const float* bx   = (const float*)d_in[6];
    const float* Wh   = (const float*)d_in[7];
    const float* bh   = (const float*)d_in[8];
    const float* wc   = (const float*)d_in[9];
    const float* bg   = (const float*)d_in[10];
    const float* Wlin = (const float*)d_in[11];
    const float* blin = (const float*)d_in[12];

    const int N = in_sizes[0] / NF;          // 500000
    const int ntiles = N / TILE;             // 15625 (N % 32 == 0)

    float* out = (float*)d_out;              // [N,1]
    float* h0o = out + N;                    // [N,32]
    float* co  = h0o + (size_t)N * NH;       // [N,32]

    short* Wpack = (short*)d_ws;                                   // 16384 B
    float* wcs   = (float*)((char*)d_ws + 4 * 4 * 64 * 8 * sizeof(short));

    prep_kernel<<<4, 256, 0, stream>>>(Wx, Wh, bx, bh, bg, wc, Wpack, wcs);

    const int grid = 768;                    // 3 blocks/CU (48KB LDS, <=170 VGPR)
    const int wstride = grid * 4;            // 3072 waves
    lstm_pipe_kernel<<<grid, 256, 0, stream>>>(
        x, h, c, Wlin, blin, Wpack, wcs, out, h0o, co, ntiles, wstride);
}

// Round 11
// 57.960 us; speedup vs baseline: 2.0924x; 2.0924x over previous
//
#include <hip/hip_runtime.h>
#include <hip/hip_bf16.h>

#define NF 16
#define NH 32
#define LOG2E  1.44269504088896340736f
#define TILE_NODES 32

// per-wave LDS staging buffer layout (float words)
#define T_WORDS 2560   // x 512 + h 1024 + c 1024 words = 10 KB
#define XW 0
#define HW 512
#define CW 1536
// output-transpose overlay (reuses consumed input space, stride 36 floats)
#define HOUT 0         // words 0..1151
#define COUT 1152      // words 1152..2303

typedef short bf16x8 __attribute__((ext_vector_type(8)));
typedef float f32x16 __attribute__((ext_vector_type(16)));
typedef float f32x4  __attribute__((ext_vector_type(4)));

#if __has_builtin(__builtin_amdgcn_exp2f)
#define EXP2(x) __builtin_amdgcn_exp2f(x)
#else
#define EXP2(x) exp2f(x)
#endif

__device__ __forceinline__ short f2bf(float f) {
    __hip_bfloat16 b = __float2bfloat16(f);  // RNE
    return *reinterpret_cast<short*>(&b);
}

__device__ __forceinline__ bf16x8 cvt8(float4 a, float4 b) {
    bf16x8 r;
    r[0] = f2bf(a.x); r[1] = f2bf(a.y); r[2] = f2bf(a.z); r[3] = f2bf(a.w);
    r[4] = f2bf(b.x); r[5] = f2bf(b.y); r[6] = f2bf(b.z); r[7] = f2bf(b.w);
    return r;
}

__device__ __forceinline__ float sig2(float v) {   // arg pre-scaled by log2e
    return __builtin_amdgcn_rcpf(1.0f + EXP2(-v));
}
__device__ __forceinline__ float tanh2(float v) {  // arg pre-scaled by 2*log2e
    return 1.0f - 2.0f * __builtin_amdgcn_rcpf(1.0f + EXP2(v));
}

// async global->LDS, 16B per lane, LDS dest = uniform base + lane*16
__device__ __forceinline__ void gload_lds16(const float* g, float* l) {
    __builtin_amdgcn_global_load_lds(
        (const __attribute__((address_space(1))) void*)g,
        (__attribute__((address_space(3))) void*)l, 16, 0, 0);
}

// non-temporal 16B store (clang ext_vector type required by the builtin)
__device__ __forceinline__ void nt_store4(float* p, float4 v) {
    f32x4 w = { v.x, v.y, v.z, v.w };
    __builtin_nontemporal_store(w, (f32x4*)p);
}

struct Frags { bf16x8 w[4][4]; bf16x8 a3; };

// ---------------------------------------------------------------------------
// Prep: pack W' = [Wx; Wh; bias; pad] (64x32 per gate, pre-scaled by log2e,
// gate 2 by 2*log2e) into MFMA A-operand fragments. wcs = scaled peephole.
// ---------------------------------------------------------------------------
__global__ void prep_kernel(const float* __restrict__ Wx, const float* __restrict__ Wh,
                            const float* __restrict__ bx, const float* __restrict__ bh,
                            const float* __restrict__ bg, const float* __restrict__ wc,
                            short* __restrict__ Wpack, float* __restrict__ wcs)
{
    int t = blockIdx.x * blockDim.x + threadIdx.x;
    if (t < 4 * 4 * 64) {
        int g  = t >> 8;
        int ks = (t >> 6) & 3;
        int l  = t & 63;
        int col  = l & 31;
        int half = l >> 5;
        float scale = (g == 2) ? 2.0f * LOG2E : LOG2E;
        #pragma unroll
        for (int e = 0; e < 8; ++e) {
            int gk = ks * 16 + half * 8 + e;
            float w;
            if (gk < NF)            w = Wx[(g * NF + gk) * NH + col];
            else if (gk < NF + NH)  w = Wh[(g * NH + (gk - NF)) * NH + col];
            else if (gk == 48)      w = bx[g * NH + col] + bh[g * NH + col] + bg[g * NH + col];
            else                    w = 0.0f;
            Wpack[t * 8 + e] = f2bf(w * scale);
        }
    }
    if (t < 3 * NH) wcs[t] = wc[t] * LOG2E;
}

// ---------------------------------------------------------------------------
// Prefetch one 32-node tile (x,h,c) into a wave-private LDS buffer via 10
// global_load_lds. Per-lane source offsets are precomputed (XOR-pre-swizzled
// within each row so the linear LDS image reads conflict-free at 128B rows).
// ---------------------------------------------------------------------------
__device__ __forceinline__ void prefetch_tile(const float* __restrict__ x,
                                              const float* __restrict__ hin,
                                              const float* __restrict__ cin,
                                              long nb, float* ws,
                                              const int* xoff, const int* hoff)
{
    asm volatile("" ::: "memory");   // pin issue order around the DMA group
    const float* xb = x   + nb * NF;
    const float* hb = hin + nb * NH;
    const float* cb = cin + nb * NH;
    #pragma unroll
    for (int i = 0; i < 2; ++i) gload_lds16(xb + xoff[i], ws + XW + i * 256);
    #pragma unroll
    for (int i = 0; i < 4; ++i) gload_lds16(hb + hoff[i], ws + HW + i * 256);
    #pragma unroll
    for (int i = 0; i < 4; ++i) gload_lds16(cb + hoff[i], ws + CW + i * 256);
    asm volatile("" ::: "memory");
}

// ---------------------------------------------------------------------------
// Consume one staged 32-node tile. Swapped-operand MFMA: D[row=j][col=node];
// lane owns node nb+(lane&31). Outputs transposed through the (consumed)
// input LDS region, stored non-temporally as coalesced 1KB rows.
// ---------------------------------------------------------------------------
__device__ __forceinline__ void do_tile(float* ws, long nb, const Frags& F,
                                        const float* __restrict__ wcs,
                                        const float* __restrict__ Wlin, float bl,
                                        float* __restrict__ out,
                                        float* __restrict__ h0o,
                                        float* __restrict__ co, int lane)
{
    const int col  = lane & 31;
    const int half = lane >> 5;
    const int c3 = col & 3, c7 = col & 7;

    // ---- fragment reads from LDS (swizzle matches prefetch source) ----
    float4 x0 = *(const float4*)&ws[XW + (col * 4 + ((2 * half)     ^ c3)) * 4];
    float4 x1 = *(const float4*)&ws[XW + (col * 4 + ((2 * half + 1) ^ c3)) * 4];
    float4 h0 = *(const float4*)&ws[HW + (col * 8 + ((2 * half)     ^ c7)) * 4];
    float4 h1 = *(const float4*)&ws[HW + (col * 8 + ((2 * half + 1) ^ c7)) * 4];
    float4 h2 = *(const float4*)&ws[HW + (col * 8 + ((4 + 2 * half) ^ c7)) * 4];
    float4 h3 = *(const float4*)&ws[HW + (col * 8 + ((5 + 2 * half) ^ c7)) * 4];
    bf16x8 a0 = cvt8(x0, x1), a1 = cvt8(h0, h1), a2 = cvt8(h2, h3);

    float4 cv4[4];
    #pragma unroll
    for (int jg = 0; jg < 4; ++jg)
        cv4[jg] = *(const float4*)&ws[CW + (col * 8 + ((2 * jg + half) ^ c7)) * 4];

    // ---- 16 MFMAs: 4 gates x K=64 (bias folded) ----
    f32x16 acc[4];
    #pragma unroll
    for (int g = 0; g < 4; ++g) {
        #pragma unroll
        for (int r = 0; r < 16; ++r) acc[g][r] = 0.0f;
        acc[g] = __builtin_amdgcn_mfma_f32_32x32x16_bf16(F.w[g][0], a0,   acc[g], 0, 0, 0);
        acc[g] = __builtin_amdgcn_mfma_f32_32x32x16_bf16(F.w[g][1], a1,   acc[g], 0, 0, 0);
        acc[g] = __builtin_amdgcn_mfma_f32_32x32x16_bf16(F.w[g][2], a2,   acc[g], 0, 0, 0);
        acc[g] = __builtin_amdgcn_mfma_f32_32x32x16_bf16(F.w[g][3], F.a3, acc[g], 0, 0, 0);
    }

    // ---- epilogue: gates -> h/c into LDS overlay (inputs already consumed) ----
    float outacc = 0.0f;
    const float c2l = 2.0f * LOG2E;
    #pragma unroll
    for (int jg = 0; jg < 4; ++jg) {
        const int jbase = jg * 8 + 4 * half;
        const float4 w0 = *(const float4*)(wcs + 0 * NH + jbase);
        const float4 w1 = *(const float4*)(wcs + 1 * NH + jbase);
        const float4 w2 = *(const float4*)(wcs + 2 * NH + jbase);
        const float4 wl = *(const float4*)(Wlin + jbase);
        float h4[4], c4[4];
        #pragma unroll
        for (int q = 0; q < 4; ++q) {
            const int r = jg * 4 + q;
            const float ci = ((const float*)&cv4[jg])[q];
            const float ig = sig2(fmaf(((const float*)&w0)[q], ci, acc[0][r]));
            const float fg = sig2(fmaf(((const float*)&w1)[q], ci, acc[1][r]));
            const float tg = tanh2(acc[2][r]);
            const float cn = fg * ci + ig * tg;
            const float og = sig2(fmaf(((const float*)&w2)[q], cn, acc[3][r]));
            const float hh = og * tanh2(cn * c2l);
            c4[q] = cn;
            h4[q] = hh;
            outacc = fmaf(fmaxf(hh, 0.0f), ((const float*)&wl)[q], outacc);
        }
        *(float4*)&ws[HOUT + col * 36 + jbase] = make_float4(h4[0], h4[1], h4[2], h4[3]);
        *(float4*)&ws[COUT + col * 36 + jbase] = make_float4(c4[0], c4[1], c4[2], c4[3]);
    }

    // ---- coalesced non-temporal write-back: 4+4 x 1KB dwordx4 rows ----
    float* hrow = h0o + nb * NH;
    float* crow = co  + nb * NH;
    #pragma unroll
    for (int rep = 0; rep < 4; ++rep) {
        const int tt = lane + rep * 64;
        const int nd = tt >> 3, j4 = (tt & 7) * 4;
        float4 vh = *(const float4*)&ws[HOUT + nd * 36 + j4];
        float4 vc = *(const float4*)&ws[COUT + nd * 36 + j4];
        nt_store4(hrow + tt * 4, vh);
        nt_store4(crow + tt * 4, vc);
    }

    outacc += __shfl_xor(outacc, 32, 64);
    if (half == 0) __builtin_nontemporal_store(outacc + bl, &out[nb + col]);
}

// ---------------------------------------------------------------------------
// Persistent grid-stride pipeline, FIFO-exact vmcnt, NO duplicate prefetches.
// Every wave has >= 7 tiles (15625 tiles / 2048 waves), so the peels are
// always valid. Tile k is prefetched exactly once (in iteration k-2).
//   peel k=0:   vmcnt(10)  [only L(k0),L(k1)=20 out; drain L(k0)]
//   steady k:   vmcnt(19)  [newer than L(k): S(k-1)9 + L(k+1)10]
//   tail  T-2:  vmcnt(19)  [same]
//   tail  T-1:  vmcnt(9)   [newer than L(T-1): S(T-2)9 only]
// ---------------------------------------------------------------------------
__global__ __launch_bounds__(256, 2) void lstm_pipe_kernel(
    const float* __restrict__ x, const float* __restrict__ hin,
    const float* __restrict__ cin,
    const float* __restrict__ Wlin, const float* __restrict__ blin,
    const short* __restrict__ Wpack, const float* __restrict__ wcs,
    float* __restrict__ out, float* __restrict__ h0o, float* __restrict__ co,
    int ntiles, int wstride)
{
    __shared__ float bufA[4][T_WORDS];   // 40 KB
    __shared__ float bufB[4][T_WORDS];   // 40 KB

    const int lane = threadIdx.x & 63;
    const int wave = threadIdx.x >> 6;
    float* cur = bufA[wave];
    float* oth = bufB[wave];

    // one-time per wave: weight fragments (64 VGPR)
    Frags F;
    #pragma unroll
    for (int g = 0; g < 4; ++g)
        #pragma unroll
        for (int ks = 0; ks < 4; ++ks)
            F.w[g][ks] = *(const bf16x8*)(Wpack + (((g * 4) + ks) * 64 + lane) * 8);
    #pragma unroll
    for (int e = 0; e < 8; ++e) F.a3[e] = 0;
    if ((lane >> 5) == 0) F.a3[0] = (short)0x3F80;  // bf16 1.0 at k=48
    const float bl = blin[0];

    // one-time per wave: swizzled DMA source offsets (lane-constant)
    int xoff[2], hoff[4];
    #pragma unroll
    for (int i = 0; i < 2; ++i) {
        int u = i * 64 + lane;
        xoff[i] = ((u & ~3) | ((u & 3) ^ ((u >> 2) & 3))) * 4;
    }
    #pragma unroll
    for (int i = 0; i < 4; ++i) {
        int u = i * 64 + lane;
        hoff[i] = ((u & ~7) | ((u & 7) ^ ((u >> 3) & 7))) * 4;
    }

    const int S = wstride;
    int t = blockIdx.x * 4 + wave;       // 2048 waves, 15625 tiles: 7-8 tiles/wave

    // prologue: L(k0)->cur, L(k1)->oth   [20 outstanding]
    prefetch_tile(x, hin, cin, (long)t * TILE_NODES, cur, xoff, hoff);
    prefetch_tile(x, hin, cin, (long)(t + S) * TILE_NODES, oth, xoff, hoff);

    // peeled first iteration (k=0): prefetch k=2 (valid: >=7 tiles/wave)
    asm volatile("s_waitcnt vmcnt(10)" ::: "memory");
    do_tile(cur, (long)t * TILE_NODES, F, wcs, Wlin, bl, out, h0o, co, lane);
    prefetch_tile(x, hin, cin, (long)(t + 2 * S) * TILE_NODES, cur, xoff, hoff);
    { float* tmp = cur; cur = oth; oth = tmp; }
    t += S;

    // steady loop: k=1..T-3; prefetch target k+2 <= T-1 always in range
    while (t + 2 * S < ntiles) {
        asm volatile("s_waitcnt vmcnt(19)" ::: "memory");
        do_tile(cur, (long)t * TILE_NODES, F, wcs, Wlin, bl, out, h0o, co, lane);
        prefetch_tile(x, hin, cin, (long)(t + 2 * S) * TILE_NODES, cur, xoff, hoff);
        float* tmp = cur; cur = oth; oth = tmp;
        t += S;
    }

    // tail A (k=T-2): no prefetch, no swap
    asm volatile("s_waitcnt vmcnt(19)" ::: "memory");
    do_tile(cur, (long)t * TILE_NODES, F, wcs, Wlin, bl, out, h0o, co, lane);
    t += S;

    // tail B (k=T-1), if this wave has one
    if (t < ntiles) {
        asm volatile("s_waitcnt vmcnt(9)" ::: "memory");
        do_tile(oth, (long)t * TILE_NODES, F, wcs, Wlin, bl, out, h0o, co, lane);
    }
}

extern "C" void kernel_launch(void* const* d_in, const int* in_sizes, int n_in,
                              void* d_out, int out_size, void* d_ws, size_t ws_size,
                              hipStream_t stream) {
    const float* x    = (const float*)d_in[0];
    // d_in[1] = edge_index (unused, K=1 ChebConv), d_in[2] = edge_weight (unused)
    const float* h    = (const float*)d_in[3];
    const float* c    = (const float*)d_in[4];
    const float* Wx   = (const float*)d_in[5];
    const float* bx   = (const float*)d_in[6];
    const float* Wh   = (const float*)d_in[7];
    const float* bh   = (const float*)d_in[8];
    const float* wc   = (const float*)d_in[9];
    const float* bg   = (const float*)d_in[10];
    const float* Wlin = (const float*)d_in[11];
    const float* blin = (const float*)d_in[12];

    const int N = in_sizes[0] / NF;          // 500000
    const int ntiles = N / TILE_NODES;       // 15625 (N % 32 == 0)

    float* out = (float*)d_out;              // [N,1]
    float* h0o = out + N;                    // [N,32]
    float* co  = h0o + (size_t)N * NH;       // [N,32]

    short* Wpack = (short*)d_ws;                                   // 16384 B
    float* wcs   = (float*)((char*)d_ws + 4 * 4 * 64 * 8 * sizeof(short));

    prep_kernel<<<4, 256, 0, stream>>>(Wx, Wh, bx, bh, bg, wc, Wpack, wcs);

    const int grid = 512;                    // 2 blocks/CU (LDS-exact)
    const int wstride = grid * 4;            // total waves = 2048
    lstm_pipe_kernel<<<grid, 256, 0, stream>>>(
        x, h, c, Wlin, blin, Wpack, wcs, out, h0o, co, ntiles, wstride);
}